// Round 1
// baseline (860.674 us; speedup 1.0000x reference)
//
#include <hip/hip_runtime.h>

// Problem constants (from reference): B=64, T=512, N=64, M=64
constexpr int B = 64, T = 512, N = 64, M = 64;
#define DT_F (1.0f / 252.0f)
#define GAMMA_F 0.1f

__global__ void zero_out_kernel(float* __restrict__ out) {
    // out_size == B == 64; one wave zeroes it (d_out is poisoned 0xAA each call)
    out[threadIdx.x] = 0.0f;
}

// One wave (64 lanes) per (b,t) pair. 4 waves per block -> 4 consecutive t.
__global__ __launch_bounds__(256) void wealth_main_kernel(
        const float* __restrict__ action,  // (B,T,N)
        const float* __restrict__ mu,      // (B,N,T)
        const float* __restrict__ sigma,   // (B,T,N,M)
        const float* __restrict__ zeta,    // (B,T,M)
        const float* __restrict__ bt,      // (T,1)
        float* __restrict__ out) {         // (B,)
    const int lane = threadIdx.x & 63;
    const int wave = threadIdx.x >> 6;
    const int b = blockIdx.x >> 7;                   // T/4 = 128 blocks per b
    const int t = ((blockIdx.x & 127) << 2) | wave;  // 4 consecutive t per block

    // Lane decomposition for the sigma pass: c = n-chunk (4 chunks of 16 rows),
    // g = m-group (16 groups of 4 columns -> float4)
    const int c = lane >> 4;
    const int g = lane & 15;

    const size_t bt_idx = (size_t)b * T + t;
    const float*  act = action + bt_idx * N;
    const float4* sg4 = (const float4*)(sigma + bt_idx * (size_t)(N * M));
    const float4* zt4 = (const float4*)(zeta + bt_idx * M);

    // Each lane owns action[lane]; broadcast via shuffle in the inner loop.
    float a_reg = act[lane];

    // risk partial for m in [4g, 4g+4), n in [16c, 16c+16)
    float4 acc = make_float4(0.f, 0.f, 0.f, 0.f);
    const int nbase = c << 4;
#pragma unroll
    for (int i = 0; i < 16; ++i) {
        const int n = nbase + i;
        float  an = __shfl(a_reg, n);        // broadcast action[b,t,n]
        float4 s4 = sg4[n * 16 + g];         // coalesced: 64 lanes x 16B
        acc.x += an * s4.x;
        acc.y += an * s4.y;
        acc.z += an * s4.z;
        acc.w += an * s4.w;
    }
    // Reduce the 4 n-chunks (lanes differing in bits 4..5)
#pragma unroll
    for (int off = 16; off <= 32; off <<= 1) {
        acc.x += __shfl_xor(acc.x, off);
        acc.y += __shfl_xor(acc.y, off);
        acc.z += __shfl_xor(acc.z, off);
        acc.w += __shfl_xor(acc.w, off);
    }

    // (risk + zeta)^2 summed over this lane's 4 m's — only c==0 sublane group
    float sq = 0.f;
    if (c == 0) {
        float4 z = zt4[g];
        float rx = acc.x + z.x;
        float ry = acc.y + z.y;
        float rz = acc.z + z.z;
        float rw = acc.w + z.w;
        sq = rx * rx + ry * ry + rz * rz + rw * rw;
    }

    // Wealth dot: sum_n action[b,t,n] * mu[b,n,t]  (mu strided by T; L2-cached)
    float d = a_reg * mu[(size_t)b * N * T + (size_t)lane * T + t];

    // Joint full-wave xor reduction (sq is zero outside lanes 0..15)
#pragma unroll
    for (int off = 1; off < 64; off <<= 1) {
        sq += __shfl_xor(sq, off);
        d  += __shfl_xor(d, off);
    }

    if (lane == 0) {
        float val = DT_F * (d + bt[t]) - (0.5f * GAMMA_F * DT_F) * sq;
        atomicAdd(out + b, val);  // 512 adds per address, 64 addresses
    }
}

extern "C" void kernel_launch(void* const* d_in, const int* in_sizes, int n_in,
                              void* d_out, int out_size, void* d_ws, size_t ws_size,
                              hipStream_t stream) {
    const float* action = (const float*)d_in[0];
    const float* mu     = (const float*)d_in[1];
    const float* sigma  = (const float*)d_in[2];
    const float* zeta   = (const float*)d_in[3];
    const float* bt     = (const float*)d_in[4];
    float* out = (float*)d_out;

    zero_out_kernel<<<1, B, 0, stream>>>(out);
    // One wave per (b,t): B*T/4 blocks of 256 threads (4 waves each)
    wealth_main_kernel<<<(B * T) / 4, 256, 0, stream>>>(action, mu, sigma, zeta, bt, out);
}

// Round 2
// 692.793 us; speedup vs baseline: 1.2423x; 1.2423x over previous
//
#include <hip/hip_runtime.h>

// Problem constants (from reference): B=64, T=512, N=64, M=64
constexpr int B = 64, T = 512, N = 64, M = 64;
#define DT_F (1.0f / 252.0f)
#define GAMMA_F 0.1f

// Kernel 1: one wave per (b,t) pair; 4 waves/block (4 consecutive t).
// Each block writes ONE partial (sum over its 4 t) to ws[blockIdx] — pure
// store, no init required, fully deterministic (no atomics).
__global__ __launch_bounds__(256) void wealth_partial_kernel(
        const float* __restrict__ action,  // (B,T,N)
        const float* __restrict__ mu,      // (B,N,T)
        const float* __restrict__ sigma,   // (B,T,N,M)
        const float* __restrict__ zeta,    // (B,T,M)
        const float* __restrict__ bt,      // (T,1)
        float* __restrict__ partial) {     // (B*T/4,) laid out [b][128]
    __shared__ float lds_val[4];
    const int lane = threadIdx.x & 63;
    const int wave = threadIdx.x >> 6;
    const int b = blockIdx.x >> 7;                   // 128 blocks per b
    const int t = ((blockIdx.x & 127) << 2) | wave;  // 4 consecutive t per block

    // Lane decomposition for the sigma pass: c = n-chunk (4 chunks of 16 rows),
    // g = m-group (16 groups of 4 columns -> float4)
    const int c = lane >> 4;
    const int g = lane & 15;

    const size_t bt_idx = (size_t)b * T + t;
    const float*  act = action + bt_idx * N;
    const float4* sg4 = (const float4*)(sigma + bt_idx * (size_t)(N * M));
    const float4* zt4 = (const float4*)(zeta + bt_idx * M);

    // Each lane owns action[lane]; broadcast via shuffle in the inner loop.
    float a_reg = act[lane];

    // risk partial for m in [4g, 4g+4), n in [16c, 16c+16)
    float4 acc = make_float4(0.f, 0.f, 0.f, 0.f);
    const int nbase = c << 4;
#pragma unroll
    for (int i = 0; i < 16; ++i) {
        const int n = nbase + i;
        float  an = __shfl(a_reg, n);        // broadcast action[b,t,n]
        float4 s4 = sg4[n * 16 + g];         // coalesced: 4x256B fully-used segments
        acc.x += an * s4.x;
        acc.y += an * s4.y;
        acc.z += an * s4.z;
        acc.w += an * s4.w;
    }
    // Reduce the 4 n-chunks (lanes differing in bits 4..5)
#pragma unroll
    for (int off = 16; off <= 32; off <<= 1) {
        acc.x += __shfl_xor(acc.x, off);
        acc.y += __shfl_xor(acc.y, off);
        acc.z += __shfl_xor(acc.z, off);
        acc.w += __shfl_xor(acc.w, off);
    }

    // (risk + zeta)^2 summed over this lane's 4 m's — only c==0 sublane group
    float sq = 0.f;
    if (c == 0) {
        float4 z = zt4[g];
        float rx = acc.x + z.x;
        float ry = acc.y + z.y;
        float rz = acc.z + z.z;
        float rw = acc.w + z.w;
        sq = rx * rx + ry * ry + rz * rz + rw * rw;
    }

    // Wealth dot: sum_n action[b,t,n] * mu[b,n,t]  (mu strided by T; L2-cached)
    float d = a_reg * mu[(size_t)b * N * T + (size_t)lane * T + t];

    // Joint full-wave xor reduction (sq is zero outside lanes 0..15)
#pragma unroll
    for (int off = 1; off < 64; off <<= 1) {
        sq += __shfl_xor(sq, off);
        d  += __shfl_xor(d, off);
    }

    if (lane == 0)
        lds_val[wave] = DT_F * (d + bt[t]) - (0.5f * GAMMA_F * DT_F) * sq;
    __syncthreads();
    if (threadIdx.x == 0)
        partial[blockIdx.x] = lds_val[0] + lds_val[1] + lds_val[2] + lds_val[3];
}

// Kernel 2: 64 threads; thread b sums its 128 contiguous partials (512 B each,
// 32 KB total — L2-resident, ~3 us).
__global__ void wealth_finalize_kernel(const float* __restrict__ partial,
                                       float* __restrict__ out) {
    const int b = threadIdx.x;
    const float4* p4 = (const float4*)(partial + b * (T / 4));
    float s = 0.f;
#pragma unroll
    for (int i = 0; i < T / 16; ++i) {
        float4 v = p4[i];
        s += v.x + v.y + v.z + v.w;
    }
    out[b] = s;
}

extern "C" void kernel_launch(void* const* d_in, const int* in_sizes, int n_in,
                              void* d_out, int out_size, void* d_ws, size_t ws_size,
                              hipStream_t stream) {
    const float* action = (const float*)d_in[0];
    const float* mu     = (const float*)d_in[1];
    const float* sigma  = (const float*)d_in[2];
    const float* zeta   = (const float*)d_in[3];
    const float* bt     = (const float*)d_in[4];
    float* out = (float*)d_out;
    float* partial = (float*)d_ws;   // B*T/4 = 8192 floats = 32 KB

    wealth_partial_kernel<<<(B * T) / 4, 256, 0, stream>>>(
        action, mu, sigma, zeta, bt, partial);
    wealth_finalize_kernel<<<1, B, 0, stream>>>(partial, out);
}